// Round 1
// baseline (34.024 us; speedup 1.0000x reference)
//
#include <hip/hip_runtime.h>
#include <hip/hip_bf16.h>

// Problem constants (from reference)
#define NODE_V 16
#define EDGE_V 8
#define BATCH  64
#define NSEQ   256

// ---------------------------------------------------------------------------
// Nodes: x_nodes [B, N, 1] -> node_logprobs [B, N, 16]
// One block per batch b (256 threads = N). Table of 17 buckets x 16 logprobs
// built in LDS by threads 0..16, then each thread gathers its row.
// ---------------------------------------------------------------------------
__global__ void node_kernel(const float* __restrict__ xn,
                            const float* __restrict__ g0,
                            float* __restrict__ out) {
    __shared__ __align__(16) float tbl[17 * 16];
    const int b = blockIdx.x;

    if (threadIdx.x < 17) {
        const float inv = __expf(-0.5f * g0[b]) ;
        // NOTE: use expf (accurate) not __expf for table values below; inv uses
        // full-precision path too for safety:
        const float inv_acc = expf(-0.5f * g0[b]);
        (void)inv;
        const int bucket = threadIdx.x;
        const float z = 2.0f * ((float)bucket + 0.5f) / (float)NODE_V - 1.0f;
        float l[NODE_V];
        float m = -1e30f;
        #pragma unroll
        for (int v = 0; v < NODE_V; ++v) {
            const float ev = 2.0f * ((float)v + 0.5f) / (float)NODE_V - 1.0f;
            const float d  = (z - ev) * inv_acc;
            l[v] = -0.5f * d * d;
            m = fmaxf(m, l[v]);
        }
        float s = 0.0f;
        #pragma unroll
        for (int v = 0; v < NODE_V; ++v) s += expf(l[v] - m);
        const float lse = m + logf(s);
        #pragma unroll
        for (int v = 0; v < NODE_V; ++v) tbl[bucket * NODE_V + v] = l[v] - lse;
    }
    __syncthreads();

    const int idx = b * NSEQ + threadIdx.x;          // [0, B*N)
    const float x = xn[idx];
    const int bucket = (int)rintf(x);                 // half-to-even, matches jnp.round
    float4* o = (float4*)(out + (size_t)idx * NODE_V);
    const float4* t = (const float4*)&tbl[bucket * NODE_V];
    #pragma unroll
    for (int k = 0; k < 4; ++k) o[k] = t[k];
}

// ---------------------------------------------------------------------------
// Edges: x_edges [B, N, N] -> edge_logprobs [B, N, N, 8]
// Grid (256, B): block (cx, b) handles 256 contiguous elements of batch b.
// Table of 9 buckets x 8 logprobs in LDS.
// ---------------------------------------------------------------------------
__global__ void edge_kernel(const float* __restrict__ xe,
                            const float* __restrict__ g0,
                            float* __restrict__ out) {
    __shared__ __align__(16) float tbl[9 * 8];
    const int b = blockIdx.y;

    if (threadIdx.x < 9) {
        const float inv = expf(-0.5f * g0[b]);
        const int bucket = threadIdx.x;
        const float z = 2.0f * ((float)bucket + 0.5f) / (float)EDGE_V - 1.0f;
        float l[EDGE_V];
        float m = -1e30f;
        #pragma unroll
        for (int v = 0; v < EDGE_V; ++v) {
            const float ev = 2.0f * ((float)v + 0.5f) / (float)EDGE_V - 1.0f;
            const float d  = (z - ev) * inv;
            l[v] = -0.5f * d * d;
            m = fmaxf(m, l[v]);
        }
        float s = 0.0f;
        #pragma unroll
        for (int v = 0; v < EDGE_V; ++v) s += expf(l[v] - m);
        const float lse = m + logf(s);
        #pragma unroll
        for (int v = 0; v < EDGE_V; ++v) tbl[bucket * EDGE_V + v] = l[v] - lse;
    }
    __syncthreads();

    const size_t idx = (size_t)b * (NSEQ * NSEQ) + (size_t)blockIdx.x * 256 + threadIdx.x;
    const float x = xe[idx];
    const int bucket = (int)rintf(x);                 // buckets 0..8
    const float4* t = (const float4*)&tbl[bucket * EDGE_V];
    float4* o = (float4*)(out + idx * EDGE_V);
    o[0] = t[0];
    o[1] = t[1];
}

extern "C" void kernel_launch(void* const* d_in, const int* in_sizes, int n_in,
                              void* d_out, int out_size, void* d_ws, size_t ws_size,
                              hipStream_t stream) {
    const float* xn = (const float*)d_in[0];   // [64, 256, 1]
    const float* xe = (const float*)d_in[1];   // [64, 256, 256]
    const float* g0 = (const float*)d_in[2];   // [64]
    float* out = (float*)d_out;

    // node_logprobs first: 64*256*16 floats
    node_kernel<<<dim3(BATCH), dim3(NSEQ), 0, stream>>>(xn, g0, out);

    float* edge_out = out + (size_t)BATCH * NSEQ * NODE_V;
    edge_kernel<<<dim3(NSEQ * NSEQ / 256, BATCH), dim3(256), 0, stream>>>(xe, g0, edge_out);
}

// Round 2
// 28.658 us; speedup vs baseline: 1.1872x; 1.1872x over previous
//
#include <hip/hip_runtime.h>
#include <hip/hip_bf16.h>

#define NODE_V 16
#define EDGE_V 8
#define BATCH  64
#define NSEQ   256

#define EDGE_ELEMS  (BATCH * NSEQ * NSEQ)   // 4,194,304
#define EDGE_BLOCKS (EDGE_ELEMS / 1024)     // 4096 (1024 elems per block)
#define NODE_OUT_FLOATS ((size_t)BATCH * NSEQ * NODE_V)  // 262,144

// ---------------------------------------------------------------------------
// Fused kernel. Blocks [0, 4096): edges. Blocks [4096, 4160): nodes.
//
// Store coalescing: lane owns OUTPUT float4 slot q (instruction-contiguous,
// 1 KB per wave per store), and derives its source element as q>>1 (edges,
// 8 floats/elem) or q>>2 (nodes, 16 floats/elem). Adjacent lanes re-read the
// same x from L1 (same cache line) - HBM fetch unaffected.
//
// Per-batch logprob tables live in LDS: only (#buckets x V) distinct output
// values exist per batch, so no per-element transcendentals.
// ---------------------------------------------------------------------------
__global__ __launch_bounds__(256) void fused_kernel(const float* __restrict__ xn,
                                                    const float* __restrict__ xe,
                                                    const float* __restrict__ g0,
                                                    float* __restrict__ out) {
    if (blockIdx.x < EDGE_BLOCKS) {
        // ------------------------- edges -------------------------
        // row stride 12 floats (48 B): <=2-way LDS bank aliasing (free)
        __shared__ __align__(16) float tbl[9 * 12];
        const int blk = blockIdx.x;
        const int b   = blk >> 6;            // 64 blocks per batch

        if (threadIdx.x < 9) {
            const float inv = expf(-0.5f * g0[b]);
            const int bucket = threadIdx.x;
            const float z = 2.0f * ((float)bucket + 0.5f) / (float)EDGE_V - 1.0f;
            float l[EDGE_V];
            float m = -1e30f;
            #pragma unroll
            for (int v = 0; v < EDGE_V; ++v) {
                const float ev = 2.0f * ((float)v + 0.5f) / (float)EDGE_V - 1.0f;
                const float d  = (z - ev) * inv;
                l[v] = -0.5f * d * d;
                m = fmaxf(m, l[v]);
            }
            float s = 0.0f;
            #pragma unroll
            for (int v = 0; v < EDGE_V; ++v) s += expf(l[v] - m);
            const float lse = m + logf(s);
            #pragma unroll
            for (int v = 0; v < EDGE_V; ++v) tbl[bucket * 12 + v] = l[v] - lse;
        }
        __syncthreads();

        const float4* t4 = (const float4*)tbl;
        float4* o4 = (float4*)(out + NODE_OUT_FLOATS);
        const size_t qbase = (size_t)blk * 2048;     // 1024 elems * 2 float4/elem
        #pragma unroll
        for (int r = 0; r < 8; ++r) {
            const size_t q = qbase + (size_t)(r * 256 + threadIdx.x);
            const float x = xe[q >> 1];
            const int bucket = (int)rintf(x);        // 0..8, half-to-even
            o4[q] = t4[bucket * 3 + (int)(q & 1)];
        }
    } else {
        // ------------------------- nodes -------------------------
        // row stride 20 floats (80 B)
        __shared__ __align__(16) float tbl[17 * 20];
        const int b = blockIdx.x - EDGE_BLOCKS;

        if (threadIdx.x < 17) {
            const float inv = expf(-0.5f * g0[b]);
            const int bucket = threadIdx.x;
            const float z = 2.0f * ((float)bucket + 0.5f) / (float)NODE_V - 1.0f;
            float l[NODE_V];
            float m = -1e30f;
            #pragma unroll
            for (int v = 0; v < NODE_V; ++v) {
                const float ev = 2.0f * ((float)v + 0.5f) / (float)NODE_V - 1.0f;
                const float d  = (z - ev) * inv;
                l[v] = -0.5f * d * d;
                m = fmaxf(m, l[v]);
            }
            float s = 0.0f;
            #pragma unroll
            for (int v = 0; v < NODE_V; ++v) s += expf(l[v] - m);
            const float lse = m + logf(s);
            #pragma unroll
            for (int v = 0; v < NODE_V; ++v) tbl[bucket * 20 + v] = l[v] - lse;
        }
        __syncthreads();

        const float4* t4 = (const float4*)tbl;
        float4* o4 = (float4*)out;
        const size_t qbase = (size_t)b * 1024;       // 256 elems * 4 float4/elem
        #pragma unroll
        for (int r = 0; r < 4; ++r) {
            const int q = r * 256 + threadIdx.x;     // local float4 slot
            const float x = xn[b * NSEQ + (q >> 2)];
            const int bucket = (int)rintf(x);        // 0..16
            o4[qbase + q] = t4[bucket * 5 + (q & 3)];
        }
    }
}

extern "C" void kernel_launch(void* const* d_in, const int* in_sizes, int n_in,
                              void* d_out, int out_size, void* d_ws, size_t ws_size,
                              hipStream_t stream) {
    const float* xn = (const float*)d_in[0];   // [64, 256, 1]
    const float* xe = (const float*)d_in[1];   // [64, 256, 256]
    const float* g0 = (const float*)d_in[2];   // [64]
    float* out = (float*)d_out;

    fused_kernel<<<dim3(EDGE_BLOCKS + BATCH), dim3(256), 0, stream>>>(xn, xe, g0, out);
}